// Round 8
// baseline (585.946 us; speedup 1.0000x reference)
//
#include <hip/hip_runtime.h>
#include <math.h>

#define N_FEAT 128
#define N_CLASSES 40
#define BSCAT 256   // blocks for bucket histogram/scatter

typedef unsigned short u16;
typedef unsigned int u32;
typedef short bf16x8 __attribute__((ext_vector_type(8)));
typedef float f32x4 __attribute__((ext_vector_type(4)));

// ---- bf16 helpers ----
__device__ __forceinline__ u32 f2bf(float f) {
    u32 u = __float_as_uint(f);
    return (u + 0x7fffu + ((u >> 16) & 1u)) >> 16;
}
__device__ __forceinline__ u32 packbf2(float lo, float hi) {
    return f2bf(lo) | (f2bf(hi) << 16);
}
__device__ __forceinline__ float bflo(u32 v) { return __uint_as_float(v << 16); }
__device__ __forceinline__ float bfhi(u32 v) { return __uint_as_float(v & 0xffff0000u); }

// ---------------- hierarchical scan (for the bucket-hist scan) ----------------

__global__ void scan1_kernel(const int* __restrict__ cnt, int* __restrict__ outp,
                             int* __restrict__ bsum, int n) {
    __shared__ int part[256];
    int b = blockIdx.x;
    int t = threadIdx.x;
    int base = b * 1024 + t * 4;
    int v0 = 0, v1 = 0, v2 = 0, v3 = 0;
    if (base + 3 < n) {
        int4 v = *(const int4*)&cnt[base];
        v0 = v.x; v1 = v.y; v2 = v.z; v3 = v.w;
    } else {
        if (base + 0 < n) v0 = cnt[base + 0];
        if (base + 1 < n) v1 = cnt[base + 1];
        if (base + 2 < n) v2 = cnt[base + 2];
        if (base + 3 < n) v3 = cnt[base + 3];
    }
    int s = v0 + v1 + v2 + v3;
    part[t] = s;
    __syncthreads();
    #pragma unroll
    for (int off = 1; off < 256; off <<= 1) {
        int mine = part[t];
        int other = (t >= off) ? part[t - off] : 0;
        __syncthreads();
        part[t] = mine + other;
        __syncthreads();
    }
    int excl = part[t] - s;
    if (base + 0 < n) outp[base + 0] = excl;
    if (base + 1 < n) outp[base + 1] = excl + v0;
    if (base + 2 < n) outp[base + 2] = excl + v0 + v1;
    if (base + 3 < n) outp[base + 3] = excl + v0 + v1 + v2;
    if (t == 255) bsum[b] = part[255];
}

__global__ void scan2_kernel(const int* __restrict__ bsum, int* __restrict__ boff,
                             int* __restrict__ outp, int nb, int n) {
    __shared__ int part[1024];
    int t = threadIdx.x;
    int s = (t < nb) ? bsum[t] : 0;
    part[t] = s;
    __syncthreads();
    for (int off = 1; off < 1024; off <<= 1) {
        int mine = part[t];
        int other = (t >= off) ? part[t - off] : 0;
        __syncthreads();
        part[t] = mine + other;
        __syncthreads();
    }
    if (t < nb) boff[t] = part[t] - s;
    if (t == 1023) outp[n] = part[1023];
}

__global__ void scan3_kernel(int* __restrict__ outp, const int* __restrict__ boff, int n) {
    int i = blockIdx.x * blockDim.x + threadIdx.x;
    if (i < n) outp[i] += boff[i >> 10];
}

// ---------------- bucketed CSR build ----------------
// Phase A: bucket edges by dst>>8; per-(block,bucket) output runs are sequential.

__global__ void ehist_kernel(const int* __restrict__ dst, int* __restrict__ hist,
                             int E, int chunk, int NB) {
    __shared__ int cnt[512];
    int b = blockIdx.x, t = threadIdx.x;
    for (int i = t; i < NB; i += 256) cnt[i] = 0;
    __syncthreads();
    int beg = b * chunk, end = min(E, beg + chunk);
    for (int e = beg + t; e < end; e += 256) atomicAdd(&cnt[dst[e] >> 8], 1);
    __syncthreads();
    int B = gridDim.x;
    for (int d = t; d < NB; d += 256) hist[d * B + b] = cnt[d];
}

__global__ void scatterA_kernel(const int* __restrict__ src, const int* __restrict__ dst,
                                const int* __restrict__ histscan, uint2* __restrict__ pairs,
                                int E, int chunk, int NB) {
    __shared__ int base[512];
    int b = blockIdx.x, t = threadIdx.x;
    int B = gridDim.x;
    for (int d = t; d < NB; d += 256) base[d] = histscan[d * B + b];
    __syncthreads();
    int beg = b * chunk, end = min(E, beg + chunk);
    for (int e = beg + t; e < end; e += 256) {
        int dd = dst[e];
        int pos = atomicAdd(&base[dd >> 8], 1);
        pairs[pos] = make_uint2((u32)src[e], (u32)dd);
    }
}

// Phase B (two-pass): per bucket, count -> LDS scan -> rowptr+dinv, then place colidx.
// Replaces the global hist_kernel + N-scan chain entirely.
__global__ void fillB_kernel(const uint2* __restrict__ pairs, const int* __restrict__ histscan,
                             int* __restrict__ rowptr, float* __restrict__ dinv,
                             int* __restrict__ colidx, int E, int N, int NB, int B) {
    __shared__ int lcnt[256];
    __shared__ int lbase[256];
    int d = blockIdx.x, t = threadIdx.x;
    lcnt[t] = 0;
    __syncthreads();
    int beg = histscan[d * B];
    int end = (d + 1 < NB) ? histscan[(d + 1) * B] : E;
    for (int e = beg + t; e < end; e += 256)
        atomicAdd(&lcnt[pairs[e].y & 255], 1);
    __syncthreads();
    int s = lcnt[t];
    lbase[t] = s;
    __syncthreads();
    #pragma unroll
    for (int off = 1; off < 256; off <<= 1) {
        int mine = lbase[t];
        int other = (t >= off) ? lbase[t - off] : 0;
        __syncthreads();
        lbase[t] = mine + other;
        __syncthreads();
    }
    int excl = lbase[t] - s;
    int node = d * 256 + t;
    if (node < N) {
        rowptr[node] = beg + excl;
        dinv[node] = rsqrtf((float)(s + 1));   // +1 = self-loop
    }
    if (d == 0 && t == 0) rowptr[N] = E;
    __syncthreads();
    lbase[t] = beg + excl;
    lcnt[t] = 0;
    __syncthreads();
    for (int e = beg + t; e < end; e += 256) {
        uint2 p = pairs[e];
        int idx = (int)p.y & 255;
        int pos = lbase[idx] + atomicAdd(&lcnt[idx], 1);
        colidx[pos] = (int)p.x;
    }
}

// ---------------- weight conversions (one launch) ----------------

__global__ void cvt_weights(const float* __restrict__ W1, const float* __restrict__ W2,
                            const float* __restrict__ W3,
                            u16* __restrict__ W1t, u16* __restrict__ W2t, u16* __restrict__ W3t) {
    int i = blockIdx.x * blockDim.x + threadIdx.x;
    if (i < 16384) {
        int n = i & 127, k = i >> 7;
        W1t[(size_t)n * 128 + k] = (u16)f2bf(W1[(size_t)k * 128 + n]);
    } else if (i < 32768) {
        int j = i - 16384;
        int n = j & 127, k = j >> 7;
        W2t[(size_t)n * 128 + k] = (u16)f2bf(W2[(size_t)k * 128 + n]);
    } else if (i < 32768 + 6144) {
        int j = i - 32768;
        int k = j & 127, n = j >> 7;
        W3t[(size_t)n * 128 + k] = (n < N_CLASSES) ? (u16)f2bf(W3[(size_t)k * N_CLASSES + n]) : (u16)0;
    }
}

// ---------------- MFMA GEMM: [N,128] @ Wt[128n][128k] -> bf16 [N,128] ----------------

template <typename AT>
__device__ __forceinline__ bf16x8 load_a_frag(const AT* aptr);

template <>
__device__ __forceinline__ bf16x8 load_a_frag<u16>(const u16* aptr) {
    return *(const bf16x8*)aptr;
}
template <>
__device__ __forceinline__ bf16x8 load_a_frag<float>(const float* aptr) {
    float4 lo = *(const float4*)aptr;
    float4 hi = *(const float4*)(aptr + 4);
    union { u32 u[4]; bf16x8 v; } r;
    r.u[0] = packbf2(lo.x, lo.y);
    r.u[1] = packbf2(lo.z, lo.w);
    r.u[2] = packbf2(hi.x, hi.y);
    r.u[3] = packbf2(hi.z, hi.w);
    return r.v;
}

template <typename AT>
__global__ __launch_bounds__(256) void gemm128_mfma(const AT* __restrict__ Ab,
                                                    const u16* __restrict__ Wt,
                                                    u16* __restrict__ Hb, int nrows) {
    __shared__ u16 Bs[128 * 136];
    int tid = threadIdx.x;
    #pragma unroll
    for (int i = 0; i < 8; i++) {
        int c = i * 256 + tid;
        int n = c >> 4, cc = c & 15;
        *(uint4*)&Bs[n * 136 + cc * 8] = ((const uint4*)Wt)[c];
    }
    __syncthreads();
    int wave = tid >> 6, lane = tid & 63;
    int quad = lane >> 4, l16 = lane & 15;
    int rowbase = blockIdx.x * 64 + wave * 16;
    int arow = rowbase + l16; if (arow >= nrows) arow = nrows - 1;
    const AT* aptr = Ab + (size_t)arow * 128 + quad * 8;
    f32x4 acc[8];
    #pragma unroll
    for (int t = 0; t < 8; t++) acc[t] = (f32x4){0.f, 0.f, 0.f, 0.f};
    #pragma unroll
    for (int kk = 0; kk < 4; kk++) {
        bf16x8 a = load_a_frag<AT>(aptr + kk * 32);
        #pragma unroll
        for (int t = 0; t < 8; t++) {
            bf16x8 b = *(const bf16x8*)&Bs[(size_t)(t * 16 + l16) * 136 + kk * 32 + quad * 8];
            acc[t] = __builtin_amdgcn_mfma_f32_16x16x32_bf16(a, b, acc[t], 0, 0, 0);
        }
    }
    #pragma unroll
    for (int r = 0; r < 4; r++) {
        int orow = rowbase + quad * 4 + r;
        if (orow < nrows) {
            #pragma unroll
            for (int t = 0; t < 8; t++)
                Hb[(size_t)orow * 128 + t * 16 + l16] = (u16)f2bf(acc[t][r]);
        }
    }
}

// ---------------- final: bf16 [N,128] @ W3t[48n][128k] + b3, log_softmax -> fp32 [N,40] --------

__global__ __launch_bounds__(256) void gemm40_lsm(const u16* __restrict__ G,
                                                  const u16* __restrict__ W3t,
                                                  const float* __restrict__ b3,
                                                  float* __restrict__ out, int nrows) {
    __shared__ u16 Bs[48 * 136];
    __shared__ float Ls[4][16][48];
    int tid = threadIdx.x;
    for (int c = tid; c < 768; c += 256) {
        int n = c >> 4, cc = c & 15;
        *(uint4*)&Bs[n * 136 + cc * 8] = ((const uint4*)W3t)[c];
    }
    __syncthreads();
    int wave = tid >> 6, lane = tid & 63;
    int quad = lane >> 4, l16 = lane & 15;
    int rowbase = blockIdx.x * 64 + wave * 16;
    int arow = rowbase + l16; if (arow >= nrows) arow = nrows - 1;
    const u16* aptr = G + (size_t)arow * 128 + quad * 8;
    f32x4 acc[3];
    #pragma unroll
    for (int t = 0; t < 3; t++) acc[t] = (f32x4){0.f, 0.f, 0.f, 0.f};
    #pragma unroll
    for (int kk = 0; kk < 4; kk++) {
        bf16x8 a = *(const bf16x8*)(aptr + kk * 32);
        #pragma unroll
        for (int t = 0; t < 3; t++) {
            bf16x8 b = *(const bf16x8*)&Bs[(size_t)(t * 16 + l16) * 136 + kk * 32 + quad * 8];
            acc[t] = __builtin_amdgcn_mfma_f32_16x16x32_bf16(a, b, acc[t], 0, 0, 0);
        }
    }
    #pragma unroll
    for (int r = 0; r < 4; r++)
        #pragma unroll
        for (int t = 0; t < 3; t++)
            Ls[wave][quad * 4 + r][t * 16 + l16] = acc[t][r];
    __syncthreads();
    float bval = (lane < N_CLASSES) ? b3[lane] : 0.f;
    for (int r = 0; r < 16; r++) {
        int row = rowbase + r;
        float v = (lane < N_CLASSES) ? Ls[wave][r][lane] + bval : -INFINITY;
        float m = v;
        #pragma unroll
        for (int off = 32; off > 0; off >>= 1) m = fmaxf(m, __shfl_xor(m, off));
        float e = (lane < N_CLASSES) ? expf(v - m) : 0.f;
        #pragma unroll
        for (int off = 32; off > 0; off >>= 1) e += __shfl_xor(e, off);
        float ls = logf(e);
        if (lane < N_CLASSES && row < nrows)
            out[(size_t)row * N_CLASSES + lane] = v - m - ls;
    }
}

// ---------------- Aggregation: feature-sliced (4 x 32 feats), XCD-pair-pinned ----------------
// out[i,slice] = dinv[i]*( sum dinv[s]*h[s,slice] ) + dinv[i]^2*h[i,slice] [+bias,relu]
// blk%8 -> XCD (round-robin heuristic); slice=(blk%8)>>1 pins each 6.4MB feature slab
// to one XCD pair, cutting cross-XCD L2 duplication 8x -> 2x per slab.
// Wave = 4 nodes x 16 lanes; each lane u32 = 2 feats; 16 lanes = 32 feats = one 64B line.

template <int BIAS_RELU>
__global__ void agg32_sliced(const u16* __restrict__ Hb, const int* __restrict__ rowptr,
                             const int* __restrict__ colidx,
                             const float* __restrict__ dinv, const float* __restrict__ bias,
                             u16* __restrict__ Ob, int nrows) {
    int blk = blockIdx.x;
    int slice = (blk & 7) >> 1;
    int grp   = (blk >> 3) * 2 + (blk & 1);
    int tid = threadIdx.x;
    int wave = tid >> 6, lane = tid & 63;
    int sub = lane >> 4, l = lane & 15;
    int node = grp * 16 + wave * 4 + sub;
    if (node >= nrows) return;
    const u32* H32 = (const u32*)Hb;
    int soff = slice * 16 + l;              // u32 offset within the 64-u32 row
    int beg = rowptr[node], end = rowptr[node + 1];
    float di = dinv[node];
    u32 hv = H32[(size_t)node * 64 + soff];
    float ax = di * bflo(hv), ay = di * bfhi(hv);
    int j = beg;
    for (; j + 2 <= end; j += 2) {
        int s0 = colidx[j], s1 = colidx[j + 1];
        float c0 = dinv[s0], c1 = dinv[s1];
        u32 v0 = H32[(size_t)s0 * 64 + soff];
        u32 v1 = H32[(size_t)s1 * 64 + soff];
        ax += c0 * bflo(v0); ay += c0 * bfhi(v0);
        ax += c1 * bflo(v1); ay += c1 * bfhi(v1);
    }
    if (j < end) {
        int s = colidx[j];
        float c = dinv[s];
        u32 v = H32[(size_t)s * 64 + soff];
        ax += c * bflo(v); ay += c * bfhi(v);
    }
    ax *= di; ay *= di;
    if (BIAS_RELU) {
        float2 b = ((const float2*)bias)[slice * 16 + l];
        ax = fmaxf(ax + b.x, 0.f);
        ay = fmaxf(ay + b.y, 0.f);
    }
    ((u32*)Ob)[(size_t)node * 64 + soff] = packbf2(ax, ay);
}

// ---------------- launch ----------------

extern "C" void kernel_launch(void* const* d_in, const int* in_sizes, int n_in,
                              void* d_out, int out_size, void* d_ws, size_t ws_size,
                              hipStream_t stream) {
    const float* x  = (const float*)d_in[0];
    const int*   ei = (const int*)d_in[1];
    const float* W1 = (const float*)d_in[2];
    const float* b1 = (const float*)d_in[3];
    const float* W2 = (const float*)d_in[4];
    const float* b2 = (const float*)d_in[5];
    const float* W3 = (const float*)d_in[6];
    const float* b3 = (const float*)d_in[7];
    float* out = (float*)d_out;

    int N = in_sizes[0] / N_FEAT;
    int E = in_sizes[1] / 2;
    const int* src = ei;
    const int* dst = ei + E;

    char* ws = (char*)d_ws;
    size_t off = 0;
    auto alloc = [&](size_t bytes) -> char* {
        char* p = ws + off;
        off = (off + bytes + 255) & ~(size_t)255;
        return p;
    };
    int NB = (N + 255) >> 8;
    int n2 = NB * BSCAT;

    float* dinv     = (float*)alloc((size_t)N * 4);
    int*   rowptr   = (int*)  alloc((size_t)(N + 1) * 4);
    int*   colidx   = (int*)  alloc((size_t)E * 4);
    int*   hist     = (int*)  alloc((size_t)n2 * 4);
    int*   histscan = (int*)  alloc((size_t)(n2 + 1) * 4);
    int*   bsum2    = (int*)  alloc((size_t)1024 * 4);
    int*   boff2    = (int*)  alloc((size_t)1024 * 4);
    uint2* pairs    = (uint2*)alloc((size_t)E * 8);
    u16*   W1t      = (u16*)  alloc((size_t)128 * 128 * 2);
    u16*   W2t      = (u16*)  alloc((size_t)128 * 128 * 2);
    u16*   W3t      = (u16*)  alloc((size_t)48 * 128 * 2);
    u16*   Hbuf     = (u16*)  alloc((size_t)N * 128 * 2);
    u16*   Abuf     = (u16*)  alloc((size_t)N * 128 * 2);
    u16*   A2buf    = (u16*)  alloc((size_t)N * 128 * 2);

    int tpb = 256;
    int nb2 = (n2 + 1023) / 1024;
    int chunk = (E + BSCAT - 1) / BSCAT;

    // bucketed CSR build (also computes rowptr + dinv inside fillB)
    ehist_kernel<<<BSCAT, 256, 0, stream>>>(dst, hist, E, chunk, NB);
    scan1_kernel<<<nb2, 256, 0, stream>>>(hist, histscan, bsum2, n2);
    scan2_kernel<<<1, 1024, 0, stream>>>(bsum2, boff2, histscan, nb2, n2);
    scan3_kernel<<<(n2 + tpb - 1) / tpb, tpb, 0, stream>>>(histscan, boff2, n2);
    scatterA_kernel<<<BSCAT, 256, 0, stream>>>(src, dst, histscan, pairs, E, chunk, NB);
    fillB_kernel<<<NB, 256, 0, stream>>>(pairs, histscan, rowptr, dinv, colidx, E, N, NB, BSCAT);

    cvt_weights<<<(38912 + 255) / 256, 256, 0, stream>>>(W1, W2, W3, W1t, W2t, W3t);

    int gGemm = (N + 63) / 64;
    int ngrp = (N + 15) / 16;
    int gAgg = 8 * ((ngrp + 1) / 2);   // 4 slices x XCD-pair swizzle

    // layer 1 (A in fp32, converted in-register)
    gemm128_mfma<float><<<gGemm, 256, 0, stream>>>(x, W1t, Hbuf, N);
    agg32_sliced<1><<<gAgg, 256, 0, stream>>>(Hbuf, rowptr, colidx, dinv, b1, Abuf, N);
    // layer 2
    gemm128_mfma<u16><<<gGemm, 256, 0, stream>>>(Abuf, W2t, Hbuf, N);
    agg32_sliced<1><<<gAgg, 256, 0, stream>>>(Hbuf, rowptr, colidx, dinv, b2, A2buf, N);
    // layer 3 reordered by linearity: G = agg(A2); out = lsm(G @ W3 + b3)
    agg32_sliced<0><<<gAgg, 256, 0, stream>>>(A2buf, rowptr, colidx, dinv, b3, Hbuf, N);
    gemm40_lsm<<<gGemm, 256, 0, stream>>>(Hbuf, W3t, b3, out, N);
}

// Round 9
// 397.106 us; speedup vs baseline: 1.4755x; 1.4755x over previous
//
#include <hip/hip_runtime.h>
#include <math.h>

#define N_FEAT 128
#define N_CLASSES 40
#define BSCAT 256   // blocks for bucket histogram/scatter

typedef unsigned short u16;
typedef unsigned int u32;
typedef short bf16x8 __attribute__((ext_vector_type(8)));
typedef float f32x4 __attribute__((ext_vector_type(4)));

// ---- bf16 helpers ----
__device__ __forceinline__ u32 f2bf(float f) {
    u32 u = __float_as_uint(f);
    return (u + 0x7fffu + ((u >> 16) & 1u)) >> 16;
}
__device__ __forceinline__ u32 packbf2(float lo, float hi) {
    return f2bf(lo) | (f2bf(hi) << 16);
}
__device__ __forceinline__ float bflo(u32 v) { return __uint_as_float(v << 16); }
__device__ __forceinline__ float bfhi(u32 v) { return __uint_as_float(v & 0xffff0000u); }

// ---------------- hierarchical scan (bucket-hist) ----------------

__global__ void scan1_kernel(const int* __restrict__ cnt, int* __restrict__ outp,
                             int* __restrict__ bsum, int n) {
    __shared__ int part[256];
    int b = blockIdx.x;
    int t = threadIdx.x;
    int base = b * 1024 + t * 4;
    int v0 = 0, v1 = 0, v2 = 0, v3 = 0;
    if (base + 3 < n) {
        int4 v = *(const int4*)&cnt[base];
        v0 = v.x; v1 = v.y; v2 = v.z; v3 = v.w;
    } else {
        if (base + 0 < n) v0 = cnt[base + 0];
        if (base + 1 < n) v1 = cnt[base + 1];
        if (base + 2 < n) v2 = cnt[base + 2];
        if (base + 3 < n) v3 = cnt[base + 3];
    }
    int s = v0 + v1 + v2 + v3;
    part[t] = s;
    __syncthreads();
    #pragma unroll
    for (int off = 1; off < 256; off <<= 1) {
        int mine = part[t];
        int other = (t >= off) ? part[t - off] : 0;
        __syncthreads();
        part[t] = mine + other;
        __syncthreads();
    }
    int excl = part[t] - s;
    if (base + 0 < n) outp[base + 0] = excl;
    if (base + 1 < n) outp[base + 1] = excl + v0;
    if (base + 2 < n) outp[base + 2] = excl + v0 + v1;
    if (base + 3 < n) outp[base + 3] = excl + v0 + v1 + v2;
    if (t == 255) bsum[b] = part[255];
}

__global__ void scan2_kernel(const int* __restrict__ bsum, int* __restrict__ boff,
                             int* __restrict__ outp, int nb, int n) {
    __shared__ int part[1024];
    int t = threadIdx.x;
    int s = (t < nb) ? bsum[t] : 0;
    part[t] = s;
    __syncthreads();
    for (int off = 1; off < 1024; off <<= 1) {
        int mine = part[t];
        int other = (t >= off) ? part[t - off] : 0;
        __syncthreads();
        part[t] = mine + other;
        __syncthreads();
    }
    if (t < nb) boff[t] = part[t] - s;
    if (t == 1023) outp[n] = part[1023];
}

__global__ void scan3_kernel(int* __restrict__ outp, const int* __restrict__ boff, int n) {
    int i = blockIdx.x * blockDim.x + threadIdx.x;
    if (i < n) outp[i] += boff[i >> 10];
}

// ---------------- bucketed CSR build ----------------

__global__ void ehist_kernel(const int* __restrict__ dst, int* __restrict__ hist,
                             int E, int chunk, int NB) {
    __shared__ int cnt[512];
    int b = blockIdx.x, t = threadIdx.x;
    for (int i = t; i < NB; i += 256) cnt[i] = 0;
    __syncthreads();
    int beg = b * chunk, end = min(E, beg + chunk);
    for (int e = beg + t; e < end; e += 256) atomicAdd(&cnt[dst[e] >> 8], 1);
    __syncthreads();
    int B = gridDim.x;
    for (int d = t; d < NB; d += 256) hist[d * B + b] = cnt[d];
}

// packed pair: (src << 8) | (dst & 255)  — src < 2^17 so this is exact
__global__ void scatterA_kernel(const int* __restrict__ src, const int* __restrict__ dst,
                                const int* __restrict__ histscan, u32* __restrict__ pairs,
                                int E, int chunk, int NB) {
    __shared__ int base[512];
    int b = blockIdx.x, t = threadIdx.x;
    int B = gridDim.x;
    for (int d = t; d < NB; d += 256) base[d] = histscan[d * B + b];
    __syncthreads();
    int beg = b * chunk, end = min(E, beg + chunk);
    for (int e = beg + t; e < end; e += 256) {
        int dd = dst[e];
        int pos = atomicAdd(&base[dd >> 8], 1);
        pairs[pos] = ((u32)src[e] << 8) | (u32)(dd & 255);
    }
}

// Phase B (two-pass): per bucket, count -> LDS scan -> rowptr+dinv, then place colidx.
__global__ void fillB_kernel(const u32* __restrict__ pairs, const int* __restrict__ histscan,
                             int* __restrict__ rowptr, float* __restrict__ dinv,
                             int* __restrict__ colidx, int E, int N, int NB, int B) {
    __shared__ int lcnt[256];
    __shared__ int lbase[256];
    int d = blockIdx.x, t = threadIdx.x;
    lcnt[t] = 0;
    __syncthreads();
    int beg = histscan[d * B];
    int end = (d + 1 < NB) ? histscan[(d + 1) * B] : E;
    for (int e = beg + t; e < end; e += 256)
        atomicAdd(&lcnt[pairs[e] & 255u], 1);
    __syncthreads();
    int s = lcnt[t];
    lbase[t] = s;
    __syncthreads();
    #pragma unroll
    for (int off = 1; off < 256; off <<= 1) {
        int mine = lbase[t];
        int other = (t >= off) ? lbase[t - off] : 0;
        __syncthreads();
        lbase[t] = mine + other;
        __syncthreads();
    }
    int excl = lbase[t] - s;
    int node = d * 256 + t;
    if (node < N) {
        rowptr[node] = beg + excl;
        dinv[node] = rsqrtf((float)(s + 1));   // +1 = self-loop
    }
    if (d == 0 && t == 0) rowptr[N] = E;
    __syncthreads();
    lbase[t] = beg + excl;
    lcnt[t] = 0;
    __syncthreads();
    for (int e = beg + t; e < end; e += 256) {
        u32 p = pairs[e];
        int idx = (int)(p & 255u);
        int pos = lbase[idx] + atomicAdd(&lcnt[idx], 1);
        colidx[pos] = (int)(p >> 8);
    }
}

// ---------------- weight conversions (one launch) ----------------

__global__ void cvt_weights(const float* __restrict__ W1, const float* __restrict__ W2,
                            const float* __restrict__ W3,
                            u16* __restrict__ W1t, u16* __restrict__ W2t, u16* __restrict__ W3t) {
    int i = blockIdx.x * blockDim.x + threadIdx.x;
    if (i < 16384) {
        int n = i & 127, k = i >> 7;
        W1t[(size_t)n * 128 + k] = (u16)f2bf(W1[(size_t)k * 128 + n]);
    } else if (i < 32768) {
        int j = i - 16384;
        int n = j & 127, k = j >> 7;
        W2t[(size_t)n * 128 + k] = (u16)f2bf(W2[(size_t)k * 128 + n]);
    } else if (i < 32768 + 6144) {
        int j = i - 32768;
        int k = j & 127, n = j >> 7;
        W3t[(size_t)n * 128 + k] = (n < N_CLASSES) ? (u16)f2bf(W3[(size_t)k * N_CLASSES + n]) : (u16)0;
    }
}

// ---------------- MFMA GEMM: [N,128] @ Wt[128n][128k] -> bf16 [N,128] ----------------

template <typename AT>
__device__ __forceinline__ bf16x8 load_a_frag(const AT* aptr);

template <>
__device__ __forceinline__ bf16x8 load_a_frag<u16>(const u16* aptr) {
    return *(const bf16x8*)aptr;
}
template <>
__device__ __forceinline__ bf16x8 load_a_frag<float>(const float* aptr) {
    float4 lo = *(const float4*)aptr;
    float4 hi = *(const float4*)(aptr + 4);
    union { u32 u[4]; bf16x8 v; } r;
    r.u[0] = packbf2(lo.x, lo.y);
    r.u[1] = packbf2(lo.z, lo.w);
    r.u[2] = packbf2(hi.x, hi.y);
    r.u[3] = packbf2(hi.z, hi.w);
    return r.v;
}

template <typename AT>
__global__ __launch_bounds__(256) void gemm128_mfma(const AT* __restrict__ Ab,
                                                    const u16* __restrict__ Wt,
                                                    u16* __restrict__ Hb, int nrows) {
    __shared__ u16 Bs[128 * 136];
    int tid = threadIdx.x;
    #pragma unroll
    for (int i = 0; i < 8; i++) {
        int c = i * 256 + tid;
        int n = c >> 4, cc = c & 15;
        *(uint4*)&Bs[n * 136 + cc * 8] = ((const uint4*)Wt)[c];
    }
    __syncthreads();
    int wave = tid >> 6, lane = tid & 63;
    int quad = lane >> 4, l16 = lane & 15;
    int rowbase = blockIdx.x * 64 + wave * 16;
    int arow = rowbase + l16; if (arow >= nrows) arow = nrows - 1;
    const AT* aptr = Ab + (size_t)arow * 128 + quad * 8;
    f32x4 acc[8];
    #pragma unroll
    for (int t = 0; t < 8; t++) acc[t] = (f32x4){0.f, 0.f, 0.f, 0.f};
    #pragma unroll
    for (int kk = 0; kk < 4; kk++) {
        bf16x8 a = load_a_frag<AT>(aptr + kk * 32);
        #pragma unroll
        for (int t = 0; t < 8; t++) {
            bf16x8 b = *(const bf16x8*)&Bs[(size_t)(t * 16 + l16) * 136 + kk * 32 + quad * 8];
            acc[t] = __builtin_amdgcn_mfma_f32_16x16x32_bf16(a, b, acc[t], 0, 0, 0);
        }
    }
    #pragma unroll
    for (int r = 0; r < 4; r++) {
        int orow = rowbase + quad * 4 + r;
        if (orow < nrows) {
            #pragma unroll
            for (int t = 0; t < 8; t++)
                Hb[(size_t)orow * 128 + t * 16 + l16] = (u16)f2bf(acc[t][r]);
        }
    }
}

// ---------------- layer-3 GEMM: bf16 [N,128] @ W3t[48n][128k] -> bf16 logits [N,48/64-stride] ----

__global__ __launch_bounds__(256) void gemm40_bf16(const u16* __restrict__ G,
                                                   const u16* __restrict__ W3t,
                                                   u16* __restrict__ Lb, int nrows) {
    __shared__ u16 Bs[48 * 136];
    int tid = threadIdx.x;
    for (int c = tid; c < 768; c += 256) {
        int n = c >> 4, cc = c & 15;
        *(uint4*)&Bs[n * 136 + cc * 8] = ((const uint4*)W3t)[c];
    }
    __syncthreads();
    int wave = tid >> 6, lane = tid & 63;
    int quad = lane >> 4, l16 = lane & 15;
    int rowbase = blockIdx.x * 64 + wave * 16;
    int arow = rowbase + l16; if (arow >= nrows) arow = nrows - 1;
    const u16* aptr = G + (size_t)arow * 128 + quad * 8;
    f32x4 acc[3];
    #pragma unroll
    for (int t = 0; t < 3; t++) acc[t] = (f32x4){0.f, 0.f, 0.f, 0.f};
    #pragma unroll
    for (int kk = 0; kk < 4; kk++) {
        bf16x8 a = *(const bf16x8*)(aptr + kk * 32);
        #pragma unroll
        for (int t = 0; t < 3; t++) {
            bf16x8 b = *(const bf16x8*)&Bs[(size_t)(t * 16 + l16) * 136 + kk * 32 + quad * 8];
            acc[t] = __builtin_amdgcn_mfma_f32_16x16x32_bf16(a, b, acc[t], 0, 0, 0);
        }
    }
    #pragma unroll
    for (int r = 0; r < 4; r++) {
        int orow = rowbase + quad * 4 + r;
        if (orow < nrows) {
            #pragma unroll
            for (int t = 0; t < 3; t++)
                Lb[(size_t)orow * 64 + t * 16 + l16] = (u16)f2bf(acc[t][r]);
        }
    }
}

// ---------------- Aggregation (128-wide, bf16 in/out): unroll-8 main loop ----------------
// out[i] = dinv[i] * sum_{s in adj(i)} dinv[s]*h[s] + dinv[i]^2*h[i] [+ bias, relu]

template <int BIAS_RELU>
__global__ void agg128_bf16(const u16* __restrict__ Hb, const int* __restrict__ rowptr,
                            const int* __restrict__ colidx,
                            const float* __restrict__ dinv, const float* __restrict__ bias,
                            u16* __restrict__ Ob, int nrows) {
    int wave = threadIdx.x >> 6;
    int lane = threadIdx.x & 63;
    int node = blockIdx.x * (blockDim.x >> 6) + wave;
    if (node >= nrows) return;
    const u32* H32 = (const u32*)Hb;
    int beg = rowptr[node], end = rowptr[node + 1];
    float di = dinv[node];
    u32 hv = H32[(size_t)node * 64 + lane];
    float ax = di * bflo(hv), ay = di * bfhi(hv);
    int j = beg;
    for (; j + 8 <= end; j += 8) {
        int s0 = colidx[j], s1 = colidx[j + 1], s2 = colidx[j + 2], s3 = colidx[j + 3];
        int s4 = colidx[j + 4], s5 = colidx[j + 5], s6 = colidx[j + 6], s7 = colidx[j + 7];
        float c0 = dinv[s0], c1 = dinv[s1], c2 = dinv[s2], c3 = dinv[s3];
        float c4 = dinv[s4], c5 = dinv[s5], c6 = dinv[s6], c7 = dinv[s7];
        u32 v0 = H32[(size_t)s0 * 64 + lane];
        u32 v1 = H32[(size_t)s1 * 64 + lane];
        u32 v2 = H32[(size_t)s2 * 64 + lane];
        u32 v3 = H32[(size_t)s3 * 64 + lane];
        u32 v4 = H32[(size_t)s4 * 64 + lane];
        u32 v5 = H32[(size_t)s5 * 64 + lane];
        u32 v6 = H32[(size_t)s6 * 64 + lane];
        u32 v7 = H32[(size_t)s7 * 64 + lane];
        ax += c0 * bflo(v0); ay += c0 * bfhi(v0);
        ax += c1 * bflo(v1); ay += c1 * bfhi(v1);
        ax += c2 * bflo(v2); ay += c2 * bfhi(v2);
        ax += c3 * bflo(v3); ay += c3 * bfhi(v3);
        ax += c4 * bflo(v4); ay += c4 * bfhi(v4);
        ax += c5 * bflo(v5); ay += c5 * bfhi(v5);
        ax += c6 * bflo(v6); ay += c6 * bfhi(v6);
        ax += c7 * bflo(v7); ay += c7 * bfhi(v7);
    }
    for (; j + 4 <= end; j += 4) {
        int s0 = colidx[j], s1 = colidx[j + 1], s2 = colidx[j + 2], s3 = colidx[j + 3];
        float c0 = dinv[s0], c1 = dinv[s1], c2 = dinv[s2], c3 = dinv[s3];
        u32 v0 = H32[(size_t)s0 * 64 + lane];
        u32 v1 = H32[(size_t)s1 * 64 + lane];
        u32 v2 = H32[(size_t)s2 * 64 + lane];
        u32 v3 = H32[(size_t)s3 * 64 + lane];
        ax += c0 * bflo(v0); ay += c0 * bfhi(v0);
        ax += c1 * bflo(v1); ay += c1 * bfhi(v1);
        ax += c2 * bflo(v2); ay += c2 * bfhi(v2);
        ax += c3 * bflo(v3); ay += c3 * bfhi(v3);
    }
    for (; j < end; j++) {
        int s = colidx[j];
        float c = dinv[s];
        u32 v = H32[(size_t)s * 64 + lane];
        ax += c * bflo(v); ay += c * bfhi(v);
    }
    ax *= di; ay *= di;
    if (BIAS_RELU) {
        float2 b = ((const float2*)bias)[lane];
        ax = fmaxf(ax + b.x, 0.f);
        ay = fmaxf(ay + b.y, 0.f);
    }
    ((u32*)Ob)[(size_t)node * 64 + lane] = packbf2(ax, ay);
}

// ---------------- Aggregation (48-wide logits, 128B stride) + b3 + log_softmax -> fp32 [N,40] ----
// one wave per node; lanes 0..23 carry 2 feats each (cols 0..47; 40 real + 8 zero-pad).

__global__ void agg48_lsm(const u16* __restrict__ Lb, const int* __restrict__ rowptr,
                          const int* __restrict__ colidx,
                          const float* __restrict__ dinv, const float* __restrict__ b3,
                          float* __restrict__ out, int nrows) {
    int wave = threadIdx.x >> 6;
    int lane = threadIdx.x & 63;
    int node = blockIdx.x * (blockDim.x >> 6) + wave;
    if (node >= nrows) return;
    const u32* L32 = (const u32*)Lb;     // row stride 32 u32 (128 B)
    int soff = lane & 31;                // lanes 0..23 meaningful; 24..31 pad; 32..63 duplicate
    int beg = rowptr[node], end = rowptr[node + 1];
    float di = dinv[node];
    u32 hv = L32[(size_t)node * 32 + soff];
    float ax = di * bflo(hv), ay = di * bfhi(hv);
    int j = beg;
    for (; j + 8 <= end; j += 8) {
        int s0 = colidx[j], s1 = colidx[j + 1], s2 = colidx[j + 2], s3 = colidx[j + 3];
        int s4 = colidx[j + 4], s5 = colidx[j + 5], s6 = colidx[j + 6], s7 = colidx[j + 7];
        float c0 = dinv[s0], c1 = dinv[s1], c2 = dinv[s2], c3 = dinv[s3];
        float c4 = dinv[s4], c5 = dinv[s5], c6 = dinv[s6], c7 = dinv[s7];
        u32 v0 = L32[(size_t)s0 * 32 + soff];
        u32 v1 = L32[(size_t)s1 * 32 + soff];
        u32 v2 = L32[(size_t)s2 * 32 + soff];
        u32 v3 = L32[(size_t)s3 * 32 + soff];
        u32 v4 = L32[(size_t)s4 * 32 + soff];
        u32 v5 = L32[(size_t)s5 * 32 + soff];
        u32 v6 = L32[(size_t)s6 * 32 + soff];
        u32 v7 = L32[(size_t)s7 * 32 + soff];
        ax += c0 * bflo(v0); ay += c0 * bfhi(v0);
        ax += c1 * bflo(v1); ay += c1 * bfhi(v1);
        ax += c2 * bflo(v2); ay += c2 * bfhi(v2);
        ax += c3 * bflo(v3); ay += c3 * bfhi(v3);
        ax += c4 * bflo(v4); ay += c4 * bfhi(v4);
        ax += c5 * bflo(v5); ay += c5 * bfhi(v5);
        ax += c6 * bflo(v6); ay += c6 * bfhi(v6);
        ax += c7 * bflo(v7); ay += c7 * bfhi(v7);
    }
    for (; j + 4 <= end; j += 4) {
        int s0 = colidx[j], s1 = colidx[j + 1], s2 = colidx[j + 2], s3 = colidx[j + 3];
        float c0 = dinv[s0], c1 = dinv[s1], c2 = dinv[s2], c3 = dinv[s3];
        u32 v0 = L32[(size_t)s0 * 32 + soff];
        u32 v1 = L32[(size_t)s1 * 32 + soff];
        u32 v2 = L32[(size_t)s2 * 32 + soff];
        u32 v3 = L32[(size_t)s3 * 32 + soff];
        ax += c0 * bflo(v0); ay += c0 * bfhi(v0);
        ax += c1 * bflo(v1); ay += c1 * bfhi(v1);
        ax += c2 * bflo(v2); ay += c2 * bfhi(v2);
        ax += c3 * bflo(v3); ay += c3 * bfhi(v3);
    }
    for (; j < end; j++) {
        int s = colidx[j];
        float c = dinv[s];
        u32 v = L32[(size_t)s * 32 + soff];
        ax += c * bflo(v); ay += c * bfhi(v);
    }
    ax *= di; ay *= di;
    // bias + validity (feats 2*lane, 2*lane+1; valid iff lane < 20)
    bool valid = lane < (N_CLASSES / 2);
    float vx = -INFINITY, vy = -INFINITY;
    if (valid) {
        float2 b = ((const float2*)b3)[lane];
        vx = ax + b.x;
        vy = ay + b.y;
    }
    float m = fmaxf(vx, vy);
    #pragma unroll
    for (int off = 32; off > 0; off >>= 1) m = fmaxf(m, __shfl_xor(m, off));
    float e = valid ? (expf(vx - m) + expf(vy - m)) : 0.f;
    #pragma unroll
    for (int off = 32; off > 0; off >>= 1) e += __shfl_xor(e, off);
    float ls = logf(e);
    if (valid) {
        float2 r; r.x = vx - m - ls; r.y = vy - m - ls;
        ((float2*)out)[(size_t)node * (N_CLASSES / 2) + lane] = r;
    }
}

// ---------------- launch ----------------

extern "C" void kernel_launch(void* const* d_in, const int* in_sizes, int n_in,
                              void* d_out, int out_size, void* d_ws, size_t ws_size,
                              hipStream_t stream) {
    const float* x  = (const float*)d_in[0];
    const int*   ei = (const int*)d_in[1];
    const float* W1 = (const float*)d_in[2];
    const float* b1 = (const float*)d_in[3];
    const float* W2 = (const float*)d_in[4];
    const float* b2 = (const float*)d_in[5];
    const float* W3 = (const float*)d_in[6];
    const float* b3 = (const float*)d_in[7];
    float* out = (float*)d_out;

    int N = in_sizes[0] / N_FEAT;
    int E = in_sizes[1] / 2;
    const int* src = ei;
    const int* dst = ei + E;

    char* ws = (char*)d_ws;
    size_t off = 0;
    auto alloc = [&](size_t bytes) -> char* {
        char* p = ws + off;
        off = (off + bytes + 255) & ~(size_t)255;
        return p;
    };
    int NB = (N + 255) >> 8;
    int n2 = NB * BSCAT;

    float* dinv     = (float*)alloc((size_t)N * 4);
    int*   rowptr   = (int*)  alloc((size_t)(N + 1) * 4);
    int*   colidx   = (int*)  alloc((size_t)E * 4);
    int*   hist     = (int*)  alloc((size_t)n2 * 4);
    int*   histscan = (int*)  alloc((size_t)(n2 + 1) * 4);
    int*   bsum2    = (int*)  alloc((size_t)1024 * 4);
    int*   boff2    = (int*)  alloc((size_t)1024 * 4);
    u32*   pairs    = (u32*)  alloc((size_t)E * 4);
    u16*   W1t      = (u16*)  alloc((size_t)128 * 128 * 2);
    u16*   W2t      = (u16*)  alloc((size_t)128 * 128 * 2);
    u16*   W3t      = (u16*)  alloc((size_t)48 * 128 * 2);
    u16*   Hbuf     = (u16*)  alloc((size_t)N * 128 * 2);
    u16*   Abuf     = (u16*)  alloc((size_t)N * 128 * 2);
    u16*   A2buf    = (u16*)  alloc((size_t)N * 128 * 2);
    u16*   Lbuf     = (u16*)  alloc((size_t)N * 64 * 2);

    int tpb = 256;
    int nb2 = (n2 + 1023) / 1024;
    int chunk = (E + BSCAT - 1) / BSCAT;

    // bucketed CSR build (rowptr + dinv computed inside fillB)
    ehist_kernel<<<BSCAT, 256, 0, stream>>>(dst, hist, E, chunk, NB);
    scan1_kernel<<<nb2, 256, 0, stream>>>(hist, histscan, bsum2, n2);
    scan2_kernel<<<1, 1024, 0, stream>>>(bsum2, boff2, histscan, nb2, n2);
    scan3_kernel<<<(n2 + tpb - 1) / tpb, tpb, 0, stream>>>(histscan, boff2, n2);
    scatterA_kernel<<<BSCAT, 256, 0, stream>>>(src, dst, histscan, pairs, E, chunk, NB);
    fillB_kernel<<<NB, 256, 0, stream>>>(pairs, histscan, rowptr, dinv, colidx, E, N, NB, BSCAT);

    cvt_weights<<<(38912 + 255) / 256, 256, 0, stream>>>(W1, W2, W3, W1t, W2t, W3t);

    int gGemm = (N + 63) / 64;
    int gAgg  = (N + 3) / 4;   // 4 waves/block, 1 node/wave

    // layer 1 (A in fp32, converted in-register)
    gemm128_mfma<float><<<gGemm, 256, 0, stream>>>(x, W1t, Hbuf, N);
    agg128_bf16<1><<<gAgg, 256, 0, stream>>>(Hbuf, rowptr, colidx, dinv, b1, Abuf, N);
    // layer 2
    gemm128_mfma<u16><<<gGemm, 256, 0, stream>>>(Abuf, W2t, Hbuf, N);
    agg128_bf16<1><<<gAgg, 256, 0, stream>>>(Hbuf, rowptr, colidx, dinv, b2, A2buf, N);
    // layer 3: L = A2 @ W3 (bf16 [N,48] in 128B-stride rows), then agg + b3 + log_softmax
    gemm40_bf16<<<gGemm, 256, 0, stream>>>(A2buf, W3t, Lbuf, N);
    agg48_lsm<<<gAgg, 256, 0, stream>>>(Lbuf, rowptr, colidx, dinv, b3, out, N);
}

// Round 10
// 359.339 us; speedup vs baseline: 1.6306x; 1.1051x over previous
//
#include <hip/hip_runtime.h>
#include <math.h>

#define N_FEAT 128
#define N_CLASSES 40
#define BSCAT 512   // blocks for bucket histogram/scatter

typedef unsigned short u16;
typedef unsigned int u32;
typedef short bf16x8 __attribute__((ext_vector_type(8)));
typedef float f32x4 __attribute__((ext_vector_type(4)));

// ---- bf16 helpers ----
__device__ __forceinline__ u32 f2bf(float f) {
    u32 u = __float_as_uint(f);
    return (u + 0x7fffu + ((u >> 16) & 1u)) >> 16;
}
__device__ __forceinline__ u32 packbf2(float lo, float hi) {
    return f2bf(lo) | (f2bf(hi) << 16);
}
__device__ __forceinline__ float bflo(u32 v) { return __uint_as_float(v << 16); }
__device__ __forceinline__ float bfhi(u32 v) { return __uint_as_float(v & 0xffff0000u); }

// ---------------- hierarchical scan (bucket-hist) ----------------

__global__ void scan1_kernel(const int* __restrict__ cnt, int* __restrict__ outp,
                             int* __restrict__ bsum, int n) {
    __shared__ int part[256];
    int b = blockIdx.x;
    int t = threadIdx.x;
    int base = b * 1024 + t * 4;
    int v0 = 0, v1 = 0, v2 = 0, v3 = 0;
    if (base + 3 < n) {
        int4 v = *(const int4*)&cnt[base];
        v0 = v.x; v1 = v.y; v2 = v.z; v3 = v.w;
    } else {
        if (base + 0 < n) v0 = cnt[base + 0];
        if (base + 1 < n) v1 = cnt[base + 1];
        if (base + 2 < n) v2 = cnt[base + 2];
        if (base + 3 < n) v3 = cnt[base + 3];
    }
    int s = v0 + v1 + v2 + v3;
    part[t] = s;
    __syncthreads();
    #pragma unroll
    for (int off = 1; off < 256; off <<= 1) {
        int mine = part[t];
        int other = (t >= off) ? part[t - off] : 0;
        __syncthreads();
        part[t] = mine + other;
        __syncthreads();
    }
    int excl = part[t] - s;
    if (base + 0 < n) outp[base + 0] = excl;
    if (base + 1 < n) outp[base + 1] = excl + v0;
    if (base + 2 < n) outp[base + 2] = excl + v0 + v1;
    if (base + 3 < n) outp[base + 3] = excl + v0 + v1 + v2;
    if (t == 255) bsum[b] = part[255];
}

__global__ void scan2_kernel(const int* __restrict__ bsum, int* __restrict__ boff,
                             int* __restrict__ outp, int nb, int n) {
    __shared__ int part[1024];
    int t = threadIdx.x;
    int s = (t < nb) ? bsum[t] : 0;
    part[t] = s;
    __syncthreads();
    for (int off = 1; off < 1024; off <<= 1) {
        int mine = part[t];
        int other = (t >= off) ? part[t - off] : 0;
        __syncthreads();
        part[t] = mine + other;
        __syncthreads();
    }
    if (t < nb) boff[t] = part[t] - s;
    if (t == 1023) outp[n] = part[1023];
}

__global__ void scan3_kernel(int* __restrict__ outp, const int* __restrict__ boff, int n) {
    int i = blockIdx.x * blockDim.x + threadIdx.x;
    if (i < n) outp[i] += boff[i >> 10];
}

// ---------------- bucketed CSR build ----------------

__global__ void ehist_kernel(const int* __restrict__ dst, int* __restrict__ hist,
                             int E, int chunk, int NB) {
    __shared__ int cnt[512];
    int b = blockIdx.x, t = threadIdx.x;
    for (int i = t; i < NB; i += 256) cnt[i] = 0;
    __syncthreads();
    int beg = b * chunk, end = min(E, beg + chunk);
    for (int e = beg + t; e < end; e += 256) atomicAdd(&cnt[dst[e] >> 8], 1);
    __syncthreads();
    int B = gridDim.x;
    for (int d = t; d < NB; d += 256) hist[d * B + b] = cnt[d];
}

// packed pair: (src << 8) | (dst & 255)  — src < 2^17 so this is exact
__global__ void scatterA_kernel(const int* __restrict__ src, const int* __restrict__ dst,
                                const int* __restrict__ histscan, u32* __restrict__ pairs,
                                int E, int chunk, int NB) {
    __shared__ int base[512];
    int b = blockIdx.x, t = threadIdx.x;
    int B = gridDim.x;
    for (int d = t; d < NB; d += 256) base[d] = histscan[d * B + b];
    __syncthreads();
    int beg = b * chunk, end = min(E, beg + chunk);
    for (int e = beg + t; e < end; e += 256) {
        int dd = dst[e];
        int pos = atomicAdd(&base[dd >> 8], 1);
        pairs[pos] = ((u32)src[e] << 8) | (u32)(dd & 255);
    }
}

// Phase B (two-pass): per bucket, count -> LDS scan -> rowptr+dinv, then place colidx.
__global__ void fillB_kernel(const u32* __restrict__ pairs, const int* __restrict__ histscan,
                             int* __restrict__ rowptr, float* __restrict__ dinv,
                             int* __restrict__ colidx, int E, int N, int NB, int B) {
    __shared__ int lcnt[256];
    __shared__ int lbase[256];
    int d = blockIdx.x, t = threadIdx.x;
    lcnt[t] = 0;
    __syncthreads();
    int beg = histscan[d * B];
    int end = (d + 1 < NB) ? histscan[(d + 1) * B] : E;
    for (int e = beg + t; e < end; e += 256)
        atomicAdd(&lcnt[pairs[e] & 255u], 1);
    __syncthreads();
    int s = lcnt[t];
    lbase[t] = s;
    __syncthreads();
    #pragma unroll
    for (int off = 1; off < 256; off <<= 1) {
        int mine = lbase[t];
        int other = (t >= off) ? lbase[t - off] : 0;
        __syncthreads();
        lbase[t] = mine + other;
        __syncthreads();
    }
    int excl = lbase[t] - s;
    int node = d * 256 + t;
    if (node < N) {
        rowptr[node] = beg + excl;
        dinv[node] = rsqrtf((float)(s + 1));   // +1 = self-loop
    }
    if (d == 0 && t == 0) rowptr[N] = E;
    __syncthreads();
    lbase[t] = beg + excl;
    lcnt[t] = 0;
    __syncthreads();
    for (int e = beg + t; e < end; e += 256) {
        u32 p = pairs[e];
        int idx = (int)(p & 255u);
        int pos = lbase[idx] + atomicAdd(&lcnt[idx], 1);
        colidx[pos] = (int)(p >> 8);
    }
}

// ---------------- weight conversions (one launch) ----------------

__global__ void cvt_weights(const float* __restrict__ W1, const float* __restrict__ W2,
                            const float* __restrict__ W3,
                            u16* __restrict__ W1t, u16* __restrict__ W2t, u16* __restrict__ W3t) {
    int i = blockIdx.x * blockDim.x + threadIdx.x;
    if (i < 16384) {
        int n = i & 127, k = i >> 7;
        W1t[(size_t)n * 128 + k] = (u16)f2bf(W1[(size_t)k * 128 + n]);
    } else if (i < 32768) {
        int j = i - 16384;
        int n = j & 127, k = j >> 7;
        W2t[(size_t)n * 128 + k] = (u16)f2bf(W2[(size_t)k * 128 + n]);
    } else if (i < 32768 + 6144) {
        int j = i - 32768;
        int k = j & 127, n = j >> 7;
        W3t[(size_t)n * 128 + k] = (n < N_CLASSES) ? (u16)f2bf(W3[(size_t)k * N_CLASSES + n]) : (u16)0;
    }
}

// ---------------- MFMA GEMM: [N,128] @ Wt[128n][128k] -> bf16 [N,128] ----------------

template <typename AT>
__device__ __forceinline__ bf16x8 load_a_frag(const AT* aptr);

template <>
__device__ __forceinline__ bf16x8 load_a_frag<u16>(const u16* aptr) {
    return *(const bf16x8*)aptr;
}
template <>
__device__ __forceinline__ bf16x8 load_a_frag<float>(const float* aptr) {
    float4 lo = *(const float4*)aptr;
    float4 hi = *(const float4*)(aptr + 4);
    union { u32 u[4]; bf16x8 v; } r;
    r.u[0] = packbf2(lo.x, lo.y);
    r.u[1] = packbf2(lo.z, lo.w);
    r.u[2] = packbf2(hi.x, hi.y);
    r.u[3] = packbf2(hi.z, hi.w);
    return r.v;
}

template <typename AT>
__global__ __launch_bounds__(256) void gemm128_mfma(const AT* __restrict__ Ab,
                                                    const u16* __restrict__ Wt,
                                                    u16* __restrict__ Hb, int nrows) {
    __shared__ u16 Bs[128 * 136];
    int tid = threadIdx.x;
    #pragma unroll
    for (int i = 0; i < 8; i++) {
        int c = i * 256 + tid;
        int n = c >> 4, cc = c & 15;
        *(uint4*)&Bs[n * 136 + cc * 8] = ((const uint4*)Wt)[c];
    }
    __syncthreads();
    int wave = tid >> 6, lane = tid & 63;
    int quad = lane >> 4, l16 = lane & 15;
    int rowbase = blockIdx.x * 64 + wave * 16;
    int arow = rowbase + l16; if (arow >= nrows) arow = nrows - 1;
    const AT* aptr = Ab + (size_t)arow * 128 + quad * 8;
    f32x4 acc[8];
    #pragma unroll
    for (int t = 0; t < 8; t++) acc[t] = (f32x4){0.f, 0.f, 0.f, 0.f};
    #pragma unroll
    for (int kk = 0; kk < 4; kk++) {
        bf16x8 a = load_a_frag<AT>(aptr + kk * 32);
        #pragma unroll
        for (int t = 0; t < 8; t++) {
            bf16x8 b = *(const bf16x8*)&Bs[(size_t)(t * 16 + l16) * 136 + kk * 32 + quad * 8];
            acc[t] = __builtin_amdgcn_mfma_f32_16x16x32_bf16(a, b, acc[t], 0, 0, 0);
        }
    }
    #pragma unroll
    for (int r = 0; r < 4; r++) {
        int orow = rowbase + quad * 4 + r;
        if (orow < nrows) {
            #pragma unroll
            for (int t = 0; t < 8; t++)
                Hb[(size_t)orow * 128 + t * 16 + l16] = (u16)f2bf(acc[t][r]);
        }
    }
}

// ---------------- layer-3 GEMM: bf16 [N,128] @ W3t[48n][128k] -> bf16 logits [N,48/64-stride] ----

__global__ __launch_bounds__(256) void gemm40_bf16(const u16* __restrict__ G,
                                                   const u16* __restrict__ W3t,
                                                   u16* __restrict__ Lb, int nrows) {
    __shared__ u16 Bs[48 * 136];
    int tid = threadIdx.x;
    for (int c = tid; c < 768; c += 256) {
        int n = c >> 4, cc = c & 15;
        *(uint4*)&Bs[n * 136 + cc * 8] = ((const uint4*)W3t)[c];
    }
    __syncthreads();
    int wave = tid >> 6, lane = tid & 63;
    int quad = lane >> 4, l16 = lane & 15;
    int rowbase = blockIdx.x * 64 + wave * 16;
    int arow = rowbase + l16; if (arow >= nrows) arow = nrows - 1;
    const u16* aptr = G + (size_t)arow * 128 + quad * 8;
    f32x4 acc[3];
    #pragma unroll
    for (int t = 0; t < 3; t++) acc[t] = (f32x4){0.f, 0.f, 0.f, 0.f};
    #pragma unroll
    for (int kk = 0; kk < 4; kk++) {
        bf16x8 a = *(const bf16x8*)(aptr + kk * 32);
        #pragma unroll
        for (int t = 0; t < 3; t++) {
            bf16x8 b = *(const bf16x8*)&Bs[(size_t)(t * 16 + l16) * 136 + kk * 32 + quad * 8];
            acc[t] = __builtin_amdgcn_mfma_f32_16x16x32_bf16(a, b, acc[t], 0, 0, 0);
        }
    }
    #pragma unroll
    for (int r = 0; r < 4; r++) {
        int orow = rowbase + quad * 4 + r;
        if (orow < nrows) {
            #pragma unroll
            for (int t = 0; t < 3; t++)
                Lb[(size_t)orow * 64 + t * 16 + l16] = (u16)f2bf(acc[t][r]);
        }
    }
}

// ---------------- Aggregation (128-wide, bf16 in/out): unroll-8 main loop ----------------
// out[i] = dinv[i] * sum_{s in adj(i)} dinv[s]*h[s] + dinv[i]^2*h[i] [+ bias, relu]

template <int BIAS_RELU>
__global__ void agg128_bf16(const u16* __restrict__ Hb, const int* __restrict__ rowptr,
                            const int* __restrict__ colidx,
                            const float* __restrict__ dinv, const float* __restrict__ bias,
                            u16* __restrict__ Ob, int nrows) {
    int wave = threadIdx.x >> 6;
    int lane = threadIdx.x & 63;
    int node = blockIdx.x * (blockDim.x >> 6) + wave;
    if (node >= nrows) return;
    const u32* H32 = (const u32*)Hb;
    int beg = rowptr[node], end = rowptr[node + 1];
    float di = dinv[node];
    u32 hv = H32[(size_t)node * 64 + lane];
    float ax = di * bflo(hv), ay = di * bfhi(hv);
    int j = beg;
    for (; j + 8 <= end; j += 8) {
        int s0 = colidx[j], s1 = colidx[j + 1], s2 = colidx[j + 2], s3 = colidx[j + 3];
        int s4 = colidx[j + 4], s5 = colidx[j + 5], s6 = colidx[j + 6], s7 = colidx[j + 7];
        float c0 = dinv[s0], c1 = dinv[s1], c2 = dinv[s2], c3 = dinv[s3];
        float c4 = dinv[s4], c5 = dinv[s5], c6 = dinv[s6], c7 = dinv[s7];
        u32 v0 = H32[(size_t)s0 * 64 + lane];
        u32 v1 = H32[(size_t)s1 * 64 + lane];
        u32 v2 = H32[(size_t)s2 * 64 + lane];
        u32 v3 = H32[(size_t)s3 * 64 + lane];
        u32 v4 = H32[(size_t)s4 * 64 + lane];
        u32 v5 = H32[(size_t)s5 * 64 + lane];
        u32 v6 = H32[(size_t)s6 * 64 + lane];
        u32 v7 = H32[(size_t)s7 * 64 + lane];
        ax += c0 * bflo(v0); ay += c0 * bfhi(v0);
        ax += c1 * bflo(v1); ay += c1 * bfhi(v1);
        ax += c2 * bflo(v2); ay += c2 * bfhi(v2);
        ax += c3 * bflo(v3); ay += c3 * bfhi(v3);
        ax += c4 * bflo(v4); ay += c4 * bfhi(v4);
        ax += c5 * bflo(v5); ay += c5 * bfhi(v5);
        ax += c6 * bflo(v6); ay += c6 * bfhi(v6);
        ax += c7 * bflo(v7); ay += c7 * bfhi(v7);
    }
    for (; j + 4 <= end; j += 4) {
        int s0 = colidx[j], s1 = colidx[j + 1], s2 = colidx[j + 2], s3 = colidx[j + 3];
        float c0 = dinv[s0], c1 = dinv[s1], c2 = dinv[s2], c3 = dinv[s3];
        u32 v0 = H32[(size_t)s0 * 64 + lane];
        u32 v1 = H32[(size_t)s1 * 64 + lane];
        u32 v2 = H32[(size_t)s2 * 64 + lane];
        u32 v3 = H32[(size_t)s3 * 64 + lane];
        ax += c0 * bflo(v0); ay += c0 * bfhi(v0);
        ax += c1 * bflo(v1); ay += c1 * bfhi(v1);
        ax += c2 * bflo(v2); ay += c2 * bfhi(v2);
        ax += c3 * bflo(v3); ay += c3 * bfhi(v3);
    }
    for (; j < end; j++) {
        int s = colidx[j];
        float c = dinv[s];
        u32 v = H32[(size_t)s * 64 + lane];
        ax += c * bflo(v); ay += c * bfhi(v);
    }
    ax *= di; ay *= di;
    if (BIAS_RELU) {
        float2 b = ((const float2*)bias)[lane];
        ax = fmaxf(ax + b.x, 0.f);
        ay = fmaxf(ay + b.y, 0.f);
    }
    ((u32*)Ob)[(size_t)node * 64 + lane] = packbf2(ax, ay);
}

// ---------------- Aggregation (48-wide logits) + b3 + log_softmax, 2 nodes/wave ----------------
// lanes 0..31 -> node A, lanes 32..63 -> node B. Per wave-instruction two edges progress,
// halving VALU cost per edge vs the one-node-per-wave version (which duplicated halves).
// Softmax reduction uses xor offsets <=16 (never crosses the 32-lane half boundary).

__global__ void agg48_lsm(const u16* __restrict__ Lb, const int* __restrict__ rowptr,
                          const int* __restrict__ colidx,
                          const float* __restrict__ dinv, const float* __restrict__ b3,
                          float* __restrict__ out, int nrows) {
    int wave = threadIdx.x >> 6;
    int half = (threadIdx.x >> 5) & 1;
    int lane = threadIdx.x & 31;
    int node = blockIdx.x * ((int)blockDim.x >> 5) + wave * 2 + half;
    if (node >= nrows) return;
    const u32* L32 = (const u32*)Lb;     // row stride 32 u32 (128 B)
    int beg = rowptr[node], end = rowptr[node + 1];
    float di = dinv[node];
    u32 hv = L32[(size_t)node * 32 + lane];
    float ax = di * bflo(hv), ay = di * bfhi(hv);
    int j = beg;
    for (; j + 8 <= end; j += 8) {
        int s0 = colidx[j], s1 = colidx[j + 1], s2 = colidx[j + 2], s3 = colidx[j + 3];
        int s4 = colidx[j + 4], s5 = colidx[j + 5], s6 = colidx[j + 6], s7 = colidx[j + 7];
        float c0 = dinv[s0], c1 = dinv[s1], c2 = dinv[s2], c3 = dinv[s3];
        float c4 = dinv[s4], c5 = dinv[s5], c6 = dinv[s6], c7 = dinv[s7];
        u32 v0 = L32[(size_t)s0 * 32 + lane];
        u32 v1 = L32[(size_t)s1 * 32 + lane];
        u32 v2 = L32[(size_t)s2 * 32 + lane];
        u32 v3 = L32[(size_t)s3 * 32 + lane];
        u32 v4 = L32[(size_t)s4 * 32 + lane];
        u32 v5 = L32[(size_t)s5 * 32 + lane];
        u32 v6 = L32[(size_t)s6 * 32 + lane];
        u32 v7 = L32[(size_t)s7 * 32 + lane];
        ax += c0 * bflo(v0); ay += c0 * bfhi(v0);
        ax += c1 * bflo(v1); ay += c1 * bfhi(v1);
        ax += c2 * bflo(v2); ay += c2 * bfhi(v2);
        ax += c3 * bflo(v3); ay += c3 * bfhi(v3);
        ax += c4 * bflo(v4); ay += c4 * bfhi(v4);
        ax += c5 * bflo(v5); ay += c5 * bfhi(v5);
        ax += c6 * bflo(v6); ay += c6 * bfhi(v6);
        ax += c7 * bflo(v7); ay += c7 * bfhi(v7);
    }
    for (; j + 4 <= end; j += 4) {
        int s0 = colidx[j], s1 = colidx[j + 1], s2 = colidx[j + 2], s3 = colidx[j + 3];
        float c0 = dinv[s0], c1 = dinv[s1], c2 = dinv[s2], c3 = dinv[s3];
        u32 v0 = L32[(size_t)s0 * 32 + lane];
        u32 v1 = L32[(size_t)s1 * 32 + lane];
        u32 v2 = L32[(size_t)s2 * 32 + lane];
        u32 v3 = L32[(size_t)s3 * 32 + lane];
        ax += c0 * bflo(v0); ay += c0 * bfhi(v0);
        ax += c1 * bflo(v1); ay += c1 * bfhi(v1);
        ax += c2 * bflo(v2); ay += c2 * bfhi(v2);
        ax += c3 * bflo(v3); ay += c3 * bfhi(v3);
    }
    for (; j < end; j++) {
        int s = colidx[j];
        float c = dinv[s];
        u32 v = L32[(size_t)s * 32 + lane];
        ax += c * bflo(v); ay += c * bfhi(v);
    }
    ax *= di; ay *= di;
    // bias + validity (feats 2*lane, 2*lane+1; valid iff lane < 20)
    bool valid = lane < (N_CLASSES / 2);
    float vx = -INFINITY, vy = -INFINITY;
    if (valid) {
        float2 b = ((const float2*)b3)[lane];
        vx = ax + b.x;
        vy = ay + b.y;
    }
    float m = fmaxf(vx, vy);
    #pragma unroll
    for (int off = 16; off > 0; off >>= 1) m = fmaxf(m, __shfl_xor(m, off));
    float e = valid ? (expf(vx - m) + expf(vy - m)) : 0.f;
    #pragma unroll
    for (int off = 16; off > 0; off >>= 1) e += __shfl_xor(e, off);
    float ls = logf(e);
    if (valid) {
        float2 r; r.x = vx - m - ls; r.y = vy - m - ls;
        ((float2*)out)[(size_t)node * (N_CLASSES / 2) + lane] = r;
    }
}

// ---------------- launch ----------------

extern "C" void kernel_launch(void* const* d_in, const int* in_sizes, int n_in,
                              void* d_out, int out_size, void* d_ws, size_t ws_size,
                              hipStream_t stream) {
    const float* x  = (const float*)d_in[0];
    const int*   ei = (const int*)d_in[1];
    const float* W1 = (const float*)d_in[2];
    const float* b1 = (const float*)d_in[3];
    const float* W2 = (const float*)d_in[4];
    const float* b2 = (const float*)d_in[5];
    const float* W3 = (const float*)d_in[6];
    const float* b3 = (const float*)d_in[7];
    float* out = (float*)d_out;

    int N = in_sizes[0] / N_FEAT;
    int E = in_sizes[1] / 2;
    const int* src = ei;
    const int* dst = ei + E;

    char* ws = (char*)d_ws;
    size_t off = 0;
    auto alloc = [&](size_t bytes) -> char* {
        char* p = ws + off;
        off = (off + bytes + 255) & ~(size_t)255;
        return p;
    };
    int NB = (N + 255) >> 8;
    int n2 = NB * BSCAT;

    float* dinv     = (float*)alloc((size_t)N * 4);
    int*   rowptr   = (int*)  alloc((size_t)(N + 1) * 4);
    int*   colidx   = (int*)  alloc((size_t)E * 4);
    int*   hist     = (int*)  alloc((size_t)n2 * 4);
    int*   histscan = (int*)  alloc((size_t)(n2 + 1) * 4);
    int*   bsum2    = (int*)  alloc((size_t)1024 * 4);
    int*   boff2    = (int*)  alloc((size_t)1024 * 4);
    u32*   pairs    = (u32*)  alloc((size_t)E * 4);
    u16*   W1t      = (u16*)  alloc((size_t)128 * 128 * 2);
    u16*   W2t      = (u16*)  alloc((size_t)128 * 128 * 2);
    u16*   W3t      = (u16*)  alloc((size_t)48 * 128 * 2);
    u16*   Hbuf     = (u16*)  alloc((size_t)N * 128 * 2);
    u16*   Abuf     = (u16*)  alloc((size_t)N * 128 * 2);
    u16*   A2buf    = (u16*)  alloc((size_t)N * 128 * 2);
    u16*   Lbuf     = (u16*)  alloc((size_t)N * 64 * 2);

    int tpb = 256;
    int nb2 = (n2 + 1023) / 1024;
    int chunk = (E + BSCAT - 1) / BSCAT;

    // bucketed CSR build (rowptr + dinv computed inside fillB)
    ehist_kernel<<<BSCAT, 256, 0, stream>>>(dst, hist, E, chunk, NB);
    scan1_kernel<<<nb2, 256, 0, stream>>>(hist, histscan, bsum2, n2);
    scan2_kernel<<<1, 1024, 0, stream>>>(bsum2, boff2, histscan, nb2, n2);
    scan3_kernel<<<(n2 + tpb - 1) / tpb, tpb, 0, stream>>>(histscan, boff2, n2);
    scatterA_kernel<<<BSCAT, 256, 0, stream>>>(src, dst, histscan, pairs, E, chunk, NB);
    fillB_kernel<<<NB, 256, 0, stream>>>(pairs, histscan, rowptr, dinv, colidx, E, N, NB, BSCAT);

    cvt_weights<<<(38912 + 255) / 256, 256, 0, stream>>>(W1, W2, W3, W1t, W2t, W3t);

    int gGemm = (N + 63) / 64;
    int gAgg  = (N + 3) / 4;    // agg128: 4 waves/block, 1 node/wave
    int gAgg48 = (N + 7) / 8;   // agg48: 4 waves/block, 2 nodes/wave

    // layer 1 (A in fp32, converted in-register)
    gemm128_mfma<float><<<gGemm, 256, 0, stream>>>(x, W1t, Hbuf, N);
    agg128_bf16<1><<<gAgg, 256, 0, stream>>>(Hbuf, rowptr, colidx, dinv, b1, Abuf, N);
    // layer 2
    gemm128_mfma<u16><<<gGemm, 256, 0, stream>>>(Abuf, W2t, Hbuf, N);
    agg128_bf16<1><<<gAgg, 256, 0, stream>>>(Hbuf, rowptr, colidx, dinv, b2, A2buf, N);
    // layer 3: L = A2 @ W3 (bf16 [N,48] in 128B-stride rows), then agg + b3 + log_softmax
    gemm40_bf16<<<gGemm, 256, 0, stream>>>(A2buf, W3t, Lbuf, N);
    agg48_lsm<<<gAgg48, 256, 0, stream>>>(Lbuf, rowptr, colidx, dinv, b3, out, N);
}